// Round 2
// baseline (333.931 us; speedup 1.0000x reference)
//
#include <hip/hip_runtime.h>

// Problem constants (fixed by the reference): B=2, S=2048, D=1024, H=16, d=64.
#define SEQ 2048
#define DM  1024
#define NH  16
#define DH  64

typedef __attribute__((ext_vector_type(8))) __bf16 bf16x8;
typedef __attribute__((ext_vector_type(4))) float f32x4;

// fp32 -> bf16 (round-to-nearest-even)
__device__ inline unsigned short f2b(float f) {
  union { float f; unsigned u; } a; a.f = f;
  unsigned u = a.u;
  u += 0x7fffu + ((u >> 16) & 1u);
  return (unsigned short)(u >> 16);
}

// async global->LDS, 16B per lane; LDS dest = uniform base + lane*16
__device__ inline void glds16(const void* g, void* s) {
  __builtin_amdgcn_global_load_lds((const __attribute__((address_space(1))) void*)g,
                                   (__attribute__((address_space(3))) void*)s,
                                   16, 0, 0);
}

// One fused fp32->bf16 convert over all 7 tensors (saves 6 launch overheads).
// Segments (in float4 units): q,k,v = 1048576 each (4096 blocks), W* = 262144
// each (1024 blocks). All segment boundaries are block-aligned.
__global__ __launch_bounds__(256) void cvt_all(
    const float* __restrict__ q, const float* __restrict__ k,
    const float* __restrict__ v, const float* __restrict__ Wq,
    const float* __restrict__ Wk, const float* __restrict__ Wv,
    const float* __restrict__ Wo, unsigned short* __restrict__ qb,
    unsigned short* __restrict__ kb, unsigned short* __restrict__ vb,
    unsigned short* __restrict__ Wqb, unsigned short* __restrict__ Wkb,
    unsigned short* __restrict__ Wvb, unsigned short* __restrict__ Wob) {
  int blk = blockIdx.x;
  const float* src;
  unsigned short* dst;
  int rel;
  if (blk < 4096)        { src = q;  dst = qb;  rel = blk; }
  else if (blk < 8192)   { src = k;  dst = kb;  rel = blk - 4096; }
  else if (blk < 12288)  { src = v;  dst = vb;  rel = blk - 8192; }
  else if (blk < 13312)  { src = Wq; dst = Wqb; rel = blk - 12288; }
  else if (blk < 14336)  { src = Wk; dst = Wkb; rel = blk - 13312; }
  else if (blk < 15360)  { src = Wv; dst = Wvb; rel = blk - 14336; }
  else                   { src = Wo; dst = Wob; rel = blk - 15360; }
  int i = rel * 256 + threadIdx.x;
  float4 val = ((const float4*)src)[i];
  ushort4 o;
  o.x = f2b(val.x); o.y = f2b(val.y); o.z = f2b(val.z); o.w = f2b(val.w);
  ((ushort4*)dst)[i] = o;
}

// C[M,N] = A[M,K] @ Bt[N,K]^T, bf16 inputs, 128x128 tile, 4 waves (2x2 of 64x64),
// 16x16x32 bf16 MFMA. A,Bt row-major with K contiguous (lda=ldb=K), ldc=N.
template<bool F32OUT>
__device__ inline void gemm_body(const unsigned short* __restrict__ A,
                                 const unsigned short* __restrict__ Bt,
                                 void* __restrict__ Cv, int N, int K) {
  __shared__ unsigned short As[128 * 64];  // [row][k], 64 bf16 per row, no pad (glds)
  __shared__ unsigned short Bs[128 * 64];
  const int tid = threadIdx.x;
  const int wave = tid >> 6, lane = tid & 63;
  const int quad = lane >> 4, l16 = lane & 15;
  const int m0 = blockIdx.y * 128, n0 = blockIdx.x * 128;
  const int wm = (wave >> 1) * 64, wn = (wave & 1) * 64;
  const int srow = lane >> 3, scol = (lane & 7) * 8;

  f32x4 acc[4][4];
#pragma unroll
  for (int i = 0; i < 4; i++)
#pragma unroll
    for (int j = 0; j < 4; j++) acc[i][j] = (f32x4)0.f;

  for (int k0 = 0; k0 < K; k0 += 64) {
#pragma unroll
    for (int c = 0; c < 4; c++) {
      int inst = wave * 4 + c;       // 16 insts cover 128 rows x 64 k
      int row = inst * 8 + srow;
      glds16(A + (size_t)(m0 + row) * K + k0 + scol, &As[inst * 512]);
      glds16(Bt + (size_t)(n0 + row) * K + k0 + scol, &Bs[inst * 512]);
    }
    __syncthreads();
#pragma unroll
    for (int ks = 0; ks < 2; ks++) {
      bf16x8 af[4], bfr[4];
#pragma unroll
      for (int i = 0; i < 4; i++)
        af[i] = *(const bf16x8*)&As[(wm + i * 16 + l16) * 64 + ks * 32 + quad * 8];
#pragma unroll
      for (int j = 0; j < 4; j++)
        bfr[j] = *(const bf16x8*)&Bs[(wn + j * 16 + l16) * 64 + ks * 32 + quad * 8];
#pragma unroll
      for (int i = 0; i < 4; i++)
#pragma unroll
        for (int j = 0; j < 4; j++)
          acc[i][j] = __builtin_amdgcn_mfma_f32_16x16x32_bf16(af[i], bfr[j],
                                                              acc[i][j], 0, 0, 0);
    }
    __syncthreads();
  }
  // C/D layout: col = lane&15, row = quad*4 + reg (m89/m91 verified)
#pragma unroll
  for (int i = 0; i < 4; i++)
#pragma unroll
    for (int j = 0; j < 4; j++)
#pragma unroll
      for (int r = 0; r < 4; r++) {
        int row = m0 + wm + i * 16 + quad * 4 + r;
        int col = n0 + wn + j * 16 + l16;
        if (F32OUT)
          ((float*)Cv)[(size_t)row * N + col] = acc[i][j][r];
        else
          ((unsigned short*)Cv)[(size_t)row * N + col] = f2b(acc[i][j][r]);
      }
}

__global__ __launch_bounds__(256) void gemm_qkv(
    const unsigned short* __restrict__ A0, const unsigned short* __restrict__ A1,
    const unsigned short* __restrict__ A2, const unsigned short* __restrict__ B0,
    const unsigned short* __restrict__ B1, const unsigned short* __restrict__ B2,
    unsigned short* __restrict__ C0, unsigned short* __restrict__ C1,
    unsigned short* __restrict__ C2) {
  const unsigned short* A = blockIdx.z == 0 ? A0 : blockIdx.z == 1 ? A1 : A2;
  const unsigned short* Bt = blockIdx.z == 0 ? B0 : blockIdx.z == 1 ? B1 : B2;
  unsigned short* C = blockIdx.z == 0 ? C0 : blockIdx.z == 1 ? C1 : C2;
  gemm_body<false>(A, Bt, (void*)C, DM, DM);
}

__global__ __launch_bounds__(256) void gemm_out(const unsigned short* __restrict__ A,
                                                const unsigned short* __restrict__ Bt,
                                                float* __restrict__ C) {
  gemm_body<true>(A, Bt, (void*)C, DM, DM);
}

// Transpose Vp (B*S x DM, per-head cols) -> Vt[(b*16+h)*64 + d][j] so attention
// PV B-fragments are 16B-contiguous global loads. One 64(j) x 64(d) tile per
// block, LDS stride 72 (16B-aligned rows, conflict-diluted).
__global__ __launch_bounds__(256) void vtrans_kernel(const unsigned short* __restrict__ Vp,
                                                     unsigned short* __restrict__ Vt) {
  __shared__ unsigned short t[64 * 72];
  const int tid = threadIdx.x;
  const int b = blockIdx.x >> 4, h = blockIdx.x & 15;
  const int j0 = blockIdx.y * 64;
  const int jr = tid >> 3, dc = (tid & 7) * 8;
#pragma unroll
  for (int r = 0; r < 2; r++) {
    int j = r * 32 + jr;
    uint4 vv = *(const uint4*)(Vp + ((size_t)b * SEQ + j0 + j) * DM + h * DH + dc);
    const unsigned short* pv = (const unsigned short*)&vv;
#pragma unroll
    for (int e = 0; e < 8; e++) t[(dc + e) * 72 + j] = pv[e];
  }
  __syncthreads();
  const int dr = tid >> 3, jc = (tid & 7) * 8;
#pragma unroll
  for (int r = 0; r < 2; r++) {
    int d = r * 32 + dr;
    uint4 vv = *(const uint4*)&t[d * 72 + jc];
    *(uint4*)(Vt + ((size_t)(b * NH + h) * DH + d) * SEQ + j0 + jc) = vv;
  }
}

// Barrier-free flash attention. Grid: (B*H, S/64 reversed). Block: 256 (4
// waves); wave w owns q rows [Q0+16w, Q0+16w+16) fully independently:
// K A-frags and Vt B-frags are direct global dwordx4 loads (L2-served); the
// only LDS is a private per-wave P layout-transform buffer (stride 72, b32
// packed writes -> ~4-way max conflicts). No __syncthreads anywhere.
__global__ __launch_bounds__(256) void attn_kernel(const unsigned short* __restrict__ Qp,
                                                   const unsigned short* __restrict__ Kp,
                                                   const unsigned short* __restrict__ Vt,
                                                   const int* __restrict__ sen_len,
                                                   unsigned short* __restrict__ ctx) {
  __shared__ unsigned int Pl[4][16 * 36];  // per-wave P: [q][j], row stride 36 u32 (72 bf16)

  const int tid = threadIdx.x;
  const int wave = tid >> 6, lane = tid & 63;
  const int quad = lane >> 4, l16 = lane & 15;
  const int b = blockIdx.x >> 4, h = blockIdx.x & 15;
  const int Q0 = (31 - (int)blockIdx.y) * 64;  // longest (causal-late) blocks first
  const int Q0w = Q0 + wave * 16;
  const int slen = sen_len[b];
  const int qrow = Q0w + l16;  // this lane's q-row for softmax stats

  // Q as B-operand: lane holds Q[q=l16][d=quad*8..] (+32 for second K=32 step)
  const size_t qbase = ((size_t)b * SEQ + qrow) * DM + h * DH;
  bf16x8 qf0 = *(const bf16x8*)(Qp + qbase + quad * 8);
  bf16x8 qf1 = *(const bf16x8*)(Qp + qbase + 32 + quad * 8);

  const unsigned short* Kb = Kp + (size_t)b * SEQ * DM + h * DH;
  const unsigned short* Vb = Vt + (size_t)(b * NH + h) * DH * SEQ;
  unsigned int* Pw = &Pl[wave][0];
  const unsigned short* Pw16 = (const unsigned short*)Pw;

  float m = -1e30f, l = 0.f;
  f32x4 o[4];
#pragma unroll
  for (int i = 0; i < 4; i++) o[i] = (f32x4)0.f;

  const int jend = (Q0w + 16 < slen) ? (Q0w + 16) : slen;  // wave-uniform

  for (int j0 = 0; j0 < jend; j0 += 64) {
    // K A-frags: lane holds K[j0 + kt*16 + l16][quad*8 ..+8] (16B contiguous)
    bf16x8 ka[4][2];
#pragma unroll
    for (int kt = 0; kt < 4; kt++) {
      const unsigned short* kr = Kb + (size_t)(j0 + kt * 16 + l16) * DM + quad * 8;
      ka[kt][0] = *(const bf16x8*)kr;
      ka[kt][1] = *(const bf16x8*)(kr + 32);
    }
    // Vt B-frags (issued early to overlap softmax): lane holds
    // Vt[d = ni*16+l16][j0 + ko*32 + quad*8 ..+8]
    bf16x8 vf[2][4];
#pragma unroll
    for (int ko = 0; ko < 2; ko++)
#pragma unroll
      for (int ni = 0; ni < 4; ni++)
        vf[ko][ni] = *(const bf16x8*)(Vb + (size_t)(ni * 16 + l16) * SEQ +
                                      j0 + ko * 32 + quad * 8);

    // S^T tiles: D[m=key][n=q]; lane holds key = kt*16 + quad*4 + r, q = l16
    f32x4 sacc[4];
#pragma unroll
    for (int kt = 0; kt < 4; kt++) sacc[kt] = (f32x4)0.f;
#pragma unroll
    for (int kt = 0; kt < 4; kt++) {
      sacc[kt] = __builtin_amdgcn_mfma_f32_16x16x32_bf16(ka[kt][0], qf0, sacc[kt], 0, 0, 0);
      sacc[kt] = __builtin_amdgcn_mfma_f32_16x16x32_bf16(ka[kt][1], qf1, sacc[kt], 0, 0, 0);
    }
    // scale + mask + per-lane max over 16 keys
    float s[4][4];
    float cmax = -1e30f;
#pragma unroll
    for (int kt = 0; kt < 4; kt++)
#pragma unroll
      for (int r = 0; r < 4; r++) {
        int j = j0 + kt * 16 + quad * 4 + r;
        float v = (j <= qrow && j < slen) ? sacc[kt][r] * 0.125f : -1e30f;
        s[kt][r] = v;
        cmax = fmaxf(cmax, v);
      }
    // q-row reduction across the 4 quads holding the same q = l16
    cmax = fmaxf(cmax, __shfl_xor(cmax, 16));
    cmax = fmaxf(cmax, __shfl_xor(cmax, 32));
    float mnew = fmaxf(m, cmax);
    float alpha = __expf(m - mnew);
    float psum = 0.f;
#pragma unroll
    for (int kt = 0; kt < 4; kt++)
#pragma unroll
      for (int rp = 0; rp < 2; rp++) {
        float p0 = __expf(s[kt][2 * rp] - mnew);
        float p1 = __expf(s[kt][2 * rp + 1] - mnew);
        psum += p0 + p1;
        Pw[l16 * 36 + kt * 8 + quad * 2 + rp] =
            (unsigned)f2b(p0) | ((unsigned)f2b(p1) << 16);
      }
    psum += __shfl_xor(psum, 16);
    psum += __shfl_xor(psum, 32);
    l = l * alpha + psum;
    m = mnew;
    // rescale ctx accumulators; ctx C-layout row q = quad*4 + r -> broadcast
    // alpha from lane quad*4 + r (same wave, q-stat holder)
#pragma unroll
    for (int r = 0; r < 4; r++) {
      float ar = __shfl(alpha, quad * 4 + r);
#pragma unroll
      for (int ni = 0; ni < 4; ni++) o[ni][r] *= ar;
    }
    // PV: D[m=q][n=d] += P[q][j] V[j][d], two K=32 steps over the 64-key chunk
#pragma unroll
    for (int ko = 0; ko < 2; ko++) {
      bf16x8 pf = *(const bf16x8*)&Pw16[l16 * 72 + ko * 32 + quad * 8];
#pragma unroll
      for (int ni = 0; ni < 4; ni++)
        o[ni] = __builtin_amdgcn_mfma_f32_16x16x32_bf16(pf, vf[ko][ni], o[ni], 0, 0, 0);
    }
  }

  // epilogue: normalize by l (per ctx-row q = quad*4 + r) and store bf16 ctx
#pragma unroll
  for (int r = 0; r < 4; r++) {
    float lr = __shfl(l, quad * 4 + r);
    float inv = 1.0f / lr;
    int row = Q0w + quad * 4 + r;
#pragma unroll
    for (int ni = 0; ni < 4; ni++) {
      float v = o[ni][r] * inv;
      ctx[((size_t)b * SEQ + row) * DM + h * DH + ni * 16 + l16] = f2b(v);
    }
  }
}

// residual add + LayerNorm, one row (1024 floats) per block
__global__ __launch_bounds__(256) void ln_kernel(const float* __restrict__ xp,
                                                 const float* __restrict__ resid,
                                                 const float* __restrict__ gamma,
                                                 const float* __restrict__ beta,
                                                 float* __restrict__ out) {
  const int row = blockIdx.x;
  const int tid = threadIdx.x;
  const size_t base = (size_t)row * DM + tid * 4;
  float4 x = *(const float4*)(xp + base);
  float4 rv = *(const float4*)(resid + base);
  x.x += rv.x; x.y += rv.y; x.z += rv.z; x.w += rv.w;
  float s = x.x + x.y + x.z + x.w;
  float s2 = x.x * x.x + x.y * x.y + x.z * x.z + x.w * x.w;
#pragma unroll
  for (int off = 1; off < 64; off <<= 1) {
    s += __shfl_xor(s, off);
    s2 += __shfl_xor(s2, off);
  }
  __shared__ float sm[4], sm2[4];
  const int wave = tid >> 6, lane = tid & 63;
  if (lane == 0) { sm[wave] = s; sm2[wave] = s2; }
  __syncthreads();
  s = sm[0] + sm[1] + sm[2] + sm[3];
  s2 = sm2[0] + sm2[1] + sm2[2] + sm2[3];
  float mean = s * (1.f / 1024.f);
  float var = s2 * (1.f / 1024.f) - mean * mean;
  float rstd = rsqrtf(var + 1e-6f);
  float4 g = *(const float4*)(gamma + tid * 4);
  float4 bt = *(const float4*)(beta + tid * 4);
  float4 o;
  o.x = (x.x - mean) * rstd * g.x + bt.x;
  o.y = (x.y - mean) * rstd * g.y + bt.y;
  o.z = (x.z - mean) * rstd * g.z + bt.z;
  o.w = (x.w - mean) * rstd * g.w + bt.w;
  *(float4*)(out + base) = o;
}

extern "C" void kernel_launch(void* const* d_in, const int* in_sizes, int n_in,
                              void* d_out, int out_size, void* d_ws, size_t ws_size,
                              hipStream_t stream) {
  const float* q     = (const float*)d_in[0];
  const float* k     = (const float*)d_in[1];
  const float* v     = (const float*)d_in[2];
  const float* Wq    = (const float*)d_in[3];
  const float* Wk    = (const float*)d_in[4];
  const float* Wv    = (const float*)d_in[5];
  const float* Wo    = (const float*)d_in[6];
  const float* gamma = (const float*)d_in[7];
  const float* beta  = (const float*)d_in[8];
  const int* sen_len = (const int*)d_in[9];
  float* out = (float*)d_out;

  char* ws = (char*)d_ws;
  const size_t MB = (size_t)1 << 20;
  if (ws_size < 64 * MB) return;  // need 64MB of scratch
  unsigned short* qb  = (unsigned short*)(ws + 0 * MB);   // dead after gemm_qkv
  unsigned short* kb  = (unsigned short*)(ws + 8 * MB);   // dead after gemm_qkv
  unsigned short* vb  = (unsigned short*)(ws + 16 * MB);  // dead after gemm_qkv
  unsigned short* Wqb = (unsigned short*)(ws + 24 * MB);
  unsigned short* Wkb = (unsigned short*)(ws + 26 * MB);
  unsigned short* Wvb = (unsigned short*)(ws + 28 * MB);
  unsigned short* Wob = (unsigned short*)(ws + 30 * MB);
  unsigned short* Qp  = (unsigned short*)(ws + 32 * MB);
  unsigned short* Kp  = (unsigned short*)(ws + 40 * MB);
  unsigned short* Vp  = (unsigned short*)(ws + 48 * MB);
  unsigned short* ctx = (unsigned short*)(ws + 56 * MB);
  unsigned short* Vt  = (unsigned short*)(ws + 0 * MB);   // 8MB, overlays dead qb
  float* outp = (float*)(ws + 8 * MB);                    // 16MB, overlays dead kb+vb

  // 1) fp32 -> bf16, single fused launch
  cvt_all<<<16384, 256, 0, stream>>>(q, k, v, Wq, Wk, Wv, Wo,
                                     qb, kb, vb, Wqb, Wkb, Wvb, Wob);

  // 2) Q/K/V projections (y = x @ W^T), fused via grid.z
  gemm_qkv<<<dim3(8, 32, 3), 256, 0, stream>>>(qb, kb, vb, Wqb, Wkb, Wvb, Qp, Kp, Vp);

  // 3) per-head transpose of V for contiguous PV B-fragments
  vtrans_kernel<<<dim3(32, 32), 256, 0, stream>>>(Vp, Vt);

  // 4) barrier-free flash attention
  attn_kernel<<<dim3(32, 32), 256, 0, stream>>>(Qp, Kp, Vt, sen_len, ctx);

  // 5) output projection (fp32 out)
  gemm_out<<<dim3(8, 32), 256, 0, stream>>>(ctx, Wob, outp);

  // 6) residual + LayerNorm
  ln_kernel<<<4096, 256, 0, stream>>>(outp, q, gamma, beta, out);
}

// Round 3
// 263.607 us; speedup vs baseline: 1.2668x; 1.2668x over previous
//
#include <hip/hip_runtime.h>

// Problem constants (fixed by the reference): B=2, S=2048, D=1024, H=16, d=64.
#define SEQ 2048
#define DM  1024
#define NH  16
#define DH  64

typedef __attribute__((ext_vector_type(8))) __bf16 bf16x8;
typedef __attribute__((ext_vector_type(4))) float f32x4;

// fp32 -> bf16 (round-to-nearest-even)
__device__ inline unsigned short f2b(float f) {
  union { float f; unsigned u; } a; a.f = f;
  unsigned u = a.u;
  u += 0x7fffu + ((u >> 16) & 1u);
  return (unsigned short)(u >> 16);
}

// async global->LDS, 16B per lane; LDS dest = uniform base + lane*16
__device__ inline void glds16(const void* g, void* s) {
  __builtin_amdgcn_global_load_lds((const __attribute__((address_space(1))) void*)g,
                                   (__attribute__((address_space(3))) void*)s,
                                   16, 0, 0);
}

// One fused fp32->bf16 convert over all 7 tensors.
__global__ __launch_bounds__(256) void cvt_all(
    const float* __restrict__ q, const float* __restrict__ k,
    const float* __restrict__ v, const float* __restrict__ Wq,
    const float* __restrict__ Wk, const float* __restrict__ Wv,
    const float* __restrict__ Wo, unsigned short* __restrict__ qb,
    unsigned short* __restrict__ kb, unsigned short* __restrict__ vb,
    unsigned short* __restrict__ Wqb, unsigned short* __restrict__ Wkb,
    unsigned short* __restrict__ Wvb, unsigned short* __restrict__ Wob) {
  int blk = blockIdx.x;
  const float* src;
  unsigned short* dst;
  int rel;
  if (blk < 4096)        { src = q;  dst = qb;  rel = blk; }
  else if (blk < 8192)   { src = k;  dst = kb;  rel = blk - 4096; }
  else if (blk < 12288)  { src = v;  dst = vb;  rel = blk - 8192; }
  else if (blk < 13312)  { src = Wq; dst = Wqb; rel = blk - 12288; }
  else if (blk < 14336)  { src = Wk; dst = Wkb; rel = blk - 13312; }
  else if (blk < 15360)  { src = Wv; dst = Wvb; rel = blk - 14336; }
  else                   { src = Wo; dst = Wob; rel = blk - 15360; }
  int i = rel * 256 + threadIdx.x;
  float4 val = ((const float4*)src)[i];
  ushort4 o;
  o.x = f2b(val.x); o.y = f2b(val.y); o.z = f2b(val.z); o.w = f2b(val.w);
  ((ushort4*)dst)[i] = o;
}

// C[M,N] = A[M,K] @ Bt[N,K]^T, bf16 inputs, 128x128 tile, 4 waves (2x2 of 64x64),
// 16x16x32 bf16 MFMA. Output MODE:
//   0 = bf16 row-major, 1 = f32 row-major,
//   2 = bf16 K-fragment-swizzle: element K[b][s][h*64+d] lands at
//       ((bh*32 + s/64)*8 + ((s>>4)&3)*2 + d/32)*512 + (((d>>3)&3)*16 + (s&15))*8 + (d&7)
//       so attn's QK A-frag load is chunk_base + lane*8 (contiguous 1KB/wave).
//   3 = bf16 V-fragment-swizzle (transposed): V[b][s][h*64+d] lands at
//       ((bh*32 + s/64)*8 + ((s&63)>>5)*4 + d/16)*512 + ((((s&63)>>3)&3)*16 + (d&15))*8 + (s&7)
//       so attn's PV B-frag load is chunk_base + lane*8.
template<int MODE>
__device__ inline void gemm_body(const unsigned short* __restrict__ A,
                                 const unsigned short* __restrict__ Bt,
                                 void* __restrict__ Cv, int N, int K) {
  __shared__ unsigned short As[128 * 64];  // [row][k], 64 bf16 per row, no pad (glds)
  __shared__ unsigned short Bs[128 * 64];
  const int tid = threadIdx.x;
  const int wave = tid >> 6, lane = tid & 63;
  const int quad = lane >> 4, l16 = lane & 15;
  const int m0 = blockIdx.y * 128, n0 = blockIdx.x * 128;
  const int wm = (wave >> 1) * 64, wn = (wave & 1) * 64;
  const int srow = lane >> 3, scol = (lane & 7) * 8;

  f32x4 acc[4][4];
#pragma unroll
  for (int i = 0; i < 4; i++)
#pragma unroll
    for (int j = 0; j < 4; j++) acc[i][j] = (f32x4)0.f;

  for (int k0 = 0; k0 < K; k0 += 64) {
#pragma unroll
    for (int c = 0; c < 4; c++) {
      int inst = wave * 4 + c;       // 16 insts cover 128 rows x 64 k
      int row = inst * 8 + srow;
      glds16(A + (size_t)(m0 + row) * K + k0 + scol, &As[inst * 512]);
      glds16(Bt + (size_t)(n0 + row) * K + k0 + scol, &Bs[inst * 512]);
    }
    __syncthreads();
#pragma unroll
    for (int ks = 0; ks < 2; ks++) {
      bf16x8 af[4], bfr[4];
#pragma unroll
      for (int i = 0; i < 4; i++)
        af[i] = *(const bf16x8*)&As[(wm + i * 16 + l16) * 64 + ks * 32 + quad * 8];
#pragma unroll
      for (int j = 0; j < 4; j++)
        bfr[j] = *(const bf16x8*)&Bs[(wn + j * 16 + l16) * 64 + ks * 32 + quad * 8];
#pragma unroll
      for (int i = 0; i < 4; i++)
#pragma unroll
        for (int j = 0; j < 4; j++)
          acc[i][j] = __builtin_amdgcn_mfma_f32_16x16x32_bf16(af[i], bfr[j],
                                                              acc[i][j], 0, 0, 0);
    }
    __syncthreads();
  }
  // C/D layout: col = lane&15, row = quad*4 + reg (m89/m91 verified)
#pragma unroll
  for (int i = 0; i < 4; i++)
#pragma unroll
    for (int j = 0; j < 4; j++)
#pragma unroll
      for (int r = 0; r < 4; r++) {
        int row = m0 + wm + i * 16 + quad * 4 + r;
        int col = n0 + wn + j * 16 + l16;
        if (MODE == 0) {
          ((unsigned short*)Cv)[(size_t)row * N + col] = f2b(acc[i][j][r]);
        } else if (MODE == 1) {
          ((float*)Cv)[(size_t)row * N + col] = acc[i][j][r];
        } else if (MODE == 2) {
          int b = row >> 11, s = row & 2047;
          int h = col >> 6, d = col & 63;
          size_t off = (((size_t)(b * NH + h) * 32 + (s >> 6)) * 8 +
                        ((s >> 4) & 3) * 2 + (d >> 5)) * 512 +
                       (((d >> 3) & 3) * 16 + (s & 15)) * 8 + (d & 7);
          ((unsigned short*)Cv)[off] = f2b(acc[i][j][r]);
        } else {
          int b = row >> 11, s = row & 2047, jj = s & 63;
          int h = col >> 6, d = col & 63;
          size_t off = (((size_t)(b * NH + h) * 32 + (s >> 6)) * 8 +
                        (jj >> 5) * 4 + (d >> 4)) * 512 +
                       (((jj >> 3) & 3) * 16 + (d & 15)) * 8 + (jj & 7);
          ((unsigned short*)Cv)[off] = f2b(acc[i][j][r]);
        }
      }
}

__global__ __launch_bounds__(256) void gemm_qkv(
    const unsigned short* __restrict__ A0, const unsigned short* __restrict__ A1,
    const unsigned short* __restrict__ A2, const unsigned short* __restrict__ B0,
    const unsigned short* __restrict__ B1, const unsigned short* __restrict__ B2,
    unsigned short* __restrict__ C0, unsigned short* __restrict__ C1,
    unsigned short* __restrict__ C2) {
  if (blockIdx.z == 0)      gemm_body<0>(A0, B0, (void*)C0, DM, DM);  // Q row-major
  else if (blockIdx.z == 1) gemm_body<2>(A1, B1, (void*)C1, DM, DM);  // K frag-swizzle
  else                      gemm_body<3>(A2, B2, (void*)C2, DM, DM);  // V frag-swizzle
}

__global__ __launch_bounds__(256) void gemm_out(const unsigned short* __restrict__ A,
                                                const unsigned short* __restrict__ Bt,
                                                float* __restrict__ C) {
  gemm_body<1>(A, Bt, (void*)C, DM, DM);
}

// Flash attention, 1 wave per block (64 thr), 16 q-rows per wave.
// Grid: (B*H, 128 q-tiles, reversed so causal-longest first). No barriers:
// K/V fragments are contiguous coalesced 1KB loads from the swizzled layouts;
// K is register-double-buffered (prefetch chunk c+1 during chunk c), V issued
// at loop top so its latency hides behind QK-MFMA + softmax. Only LDS use is
// the per-wave P layout transform (in-order DS ops, no sync needed).
__global__ __launch_bounds__(64) void attn_kernel(const unsigned short* __restrict__ Qp,
                                                  const unsigned short* __restrict__ Ksw,
                                                  const unsigned short* __restrict__ Vsw,
                                                  const int* __restrict__ sen_len,
                                                  unsigned short* __restrict__ ctx) {
  __shared__ unsigned int Pl[16 * 36];  // P: [q][j], row stride 36 u32 (72 bf16)

  const int lane = threadIdx.x;
  const int quad = lane >> 4, l16 = lane & 15;
  const int bh = blockIdx.x, b = bh >> 4, h = bh & 15;
  const int qt = 127 - (int)blockIdx.y;  // longest (causal-late) tiles first
  const int slen = sen_len[b];
  const int qrow = qt * 16 + l16;  // this lane's q-row for softmax stats

  // Q as B-operand: lane holds Q[q=l16][d=quad*8..] (+32 for second K=32 step)
  const size_t qbase = ((size_t)b * SEQ + qrow) * DM + h * DH;
  bf16x8 qf0 = *(const bf16x8*)(Qp + qbase + quad * 8);
  bf16x8 qf1 = *(const bf16x8*)(Qp + qbase + 32 + quad * 8);

  const unsigned short* kbase = Ksw + (size_t)bh * 32 * 4096 + lane * 8;
  const unsigned short* vbase = Vsw + (size_t)bh * 32 * 4096 + lane * 8;
  const unsigned short* Pw16 = (const unsigned short*)Pl;

  int jend = qt * 16 + 16;
  if (slen < jend) jend = slen;
  const int nch = (jend + 63) >> 6;  // 64-key chunks (>=1)

  float m = -1e30f, l = 0.f;
  f32x4 o[4];
#pragma unroll
  for (int i = 0; i < 4; i++) o[i] = (f32x4)0.f;

  // preload chunk 0 K-frags (8 x contiguous 1KB)
  bf16x8 ka[4][2];
#pragma unroll
  for (int fi = 0; fi < 8; fi++)
    ka[fi >> 1][fi & 1] = *(const bf16x8*)(kbase + fi * 512);

  for (int c = 0; c < nch; ++c) {
    const int j0 = c * 64;
    // V frags for current chunk — issued first, hide behind QK + softmax
    bf16x8 vf[2][4];
#pragma unroll
    for (int fi = 0; fi < 8; fi++)
      vf[fi >> 2][fi & 3] = *(const bf16x8*)(vbase + (size_t)c * 4096 + fi * 512);
    // K frags for next chunk (clamped index: harmless dead prefetch on last)
    const int cn = (c + 1 < nch) ? c + 1 : c;
    bf16x8 kn[4][2];
#pragma unroll
    for (int fi = 0; fi < 8; fi++)
      kn[fi >> 1][fi & 1] = *(const bf16x8*)(kbase + (size_t)cn * 4096 + fi * 512);

    // S^T tiles: D[m=key][n=q]; lane holds key = kt*16 + quad*4 + r, q = l16
    f32x4 sacc[4];
#pragma unroll
    for (int kt = 0; kt < 4; kt++) sacc[kt] = (f32x4)0.f;
#pragma unroll
    for (int kt = 0; kt < 4; kt++) {
      sacc[kt] = __builtin_amdgcn_mfma_f32_16x16x32_bf16(ka[kt][0], qf0, sacc[kt], 0, 0, 0);
      sacc[kt] = __builtin_amdgcn_mfma_f32_16x16x32_bf16(ka[kt][1], qf1, sacc[kt], 0, 0, 0);
    }
    // scale + mask + per-lane max (in place in sacc)
    float cmax = -1e30f;
#pragma unroll
    for (int kt = 0; kt < 4; kt++)
#pragma unroll
      for (int r = 0; r < 4; r++) {
        int j = j0 + kt * 16 + quad * 4 + r;
        float v = (j <= qrow && j < slen) ? sacc[kt][r] * 0.125f : -1e30f;
        sacc[kt][r] = v;
        cmax = fmaxf(cmax, v);
      }
    // q-row reduction across the 4 quads holding the same q = l16
    cmax = fmaxf(cmax, __shfl_xor(cmax, 16));
    cmax = fmaxf(cmax, __shfl_xor(cmax, 32));
    float mnew = fmaxf(m, cmax);
    float alpha = __expf(m - mnew);
    float psum = 0.f;
#pragma unroll
    for (int kt = 0; kt < 4; kt++)
#pragma unroll
      for (int rp = 0; rp < 2; rp++) {
        float p0 = __expf(sacc[kt][2 * rp] - mnew);
        float p1 = __expf(sacc[kt][2 * rp + 1] - mnew);
        psum += p0 + p1;
        Pl[l16 * 36 + kt * 8 + quad * 2 + rp] =
            (unsigned)f2b(p0) | ((unsigned)f2b(p1) << 16);
      }
    psum += __shfl_xor(psum, 16);
    psum += __shfl_xor(psum, 32);
    l = l * alpha + psum;
    m = mnew;
    // rescale ctx accumulators; ctx C-layout row q = quad*4 + r -> broadcast
    // alpha from lane quad*4 + r (same wave, q-stat holder)
#pragma unroll
    for (int r = 0; r < 4; r++) {
      float ar = __shfl(alpha, quad * 4 + r);
#pragma unroll
      for (int ni = 0; ni < 4; ni++) o[ni][r] *= ar;
    }
    // PV: D[m=q][n=d] += P[q][j] V[j][d], two K=32 steps over the 64-key chunk
#pragma unroll
    for (int ko = 0; ko < 2; ko++) {
      bf16x8 pf = *(const bf16x8*)&Pw16[l16 * 72 + ko * 32 + quad * 8];
#pragma unroll
      for (int ni = 0; ni < 4; ni++)
        o[ni] = __builtin_amdgcn_mfma_f32_16x16x32_bf16(pf, vf[ko][ni], o[ni], 0, 0, 0);
    }
    // rotate K double-buffer
#pragma unroll
    for (int fi = 0; fi < 8; fi++) ka[fi >> 1][fi & 1] = kn[fi >> 1][fi & 1];
  }

  // epilogue: normalize by l (per ctx-row q = quad*4 + r) and store bf16 ctx
#pragma unroll
  for (int r = 0; r < 4; r++) {
    float lr = __shfl(l, quad * 4 + r);
    float inv = 1.0f / lr;
    int row = qt * 16 + quad * 4 + r;
#pragma unroll
    for (int ni = 0; ni < 4; ni++) {
      float v = o[ni][r] * inv;
      ctx[((size_t)b * SEQ + row) * DM + h * DH + ni * 16 + l16] = f2b(v);
    }
  }
}

// residual add + LayerNorm, one row (1024 floats) per block
__global__ __launch_bounds__(256) void ln_kernel(const float* __restrict__ xp,
                                                 const float* __restrict__ resid,
                                                 const float* __restrict__ gamma,
                                                 const float* __restrict__ beta,
                                                 float* __restrict__ out) {
  const int row = blockIdx.x;
  const int tid = threadIdx.x;
  const size_t base = (size_t)row * DM + tid * 4;
  float4 x = *(const float4*)(xp + base);
  float4 rv = *(const float4*)(resid + base);
  x.x += rv.x; x.y += rv.y; x.z += rv.z; x.w += rv.w;
  float s = x.x + x.y + x.z + x.w;
  float s2 = x.x * x.x + x.y * x.y + x.z * x.z + x.w * x.w;
#pragma unroll
  for (int off = 1; off < 64; off <<= 1) {
    s += __shfl_xor(s, off);
    s2 += __shfl_xor(s2, off);
  }
  __shared__ float sm[4], sm2[4];
  const int wave = tid >> 6, lane = tid & 63;
  if (lane == 0) { sm[wave] = s; sm2[wave] = s2; }
  __syncthreads();
  s = sm[0] + sm[1] + sm[2] + sm[3];
  s2 = sm2[0] + sm2[1] + sm2[2] + sm2[3];
  float mean = s * (1.f / 1024.f);
  float var = s2 * (1.f / 1024.f) - mean * mean;
  float rstd = rsqrtf(var + 1e-6f);
  float4 g = *(const float4*)(gamma + tid * 4);
  float4 bt = *(const float4*)(beta + tid * 4);
  float4 o;
  o.x = (x.x - mean) * rstd * g.x + bt.x;
  o.y = (x.y - mean) * rstd * g.y + bt.y;
  o.z = (x.z - mean) * rstd * g.z + bt.z;
  o.w = (x.w - mean) * rstd * g.w + bt.w;
  *(float4*)(out + base) = o;
}

extern "C" void kernel_launch(void* const* d_in, const int* in_sizes, int n_in,
                              void* d_out, int out_size, void* d_ws, size_t ws_size,
                              hipStream_t stream) {
  const float* q     = (const float*)d_in[0];
  const float* k     = (const float*)d_in[1];
  const float* v     = (const float*)d_in[2];
  const float* Wq    = (const float*)d_in[3];
  const float* Wk    = (const float*)d_in[4];
  const float* Wv    = (const float*)d_in[5];
  const float* Wo    = (const float*)d_in[6];
  const float* gamma = (const float*)d_in[7];
  const float* beta  = (const float*)d_in[8];
  const int* sen_len = (const int*)d_in[9];
  float* out = (float*)d_out;

  char* ws = (char*)d_ws;
  const size_t MB = (size_t)1 << 20;
  if (ws_size < 64 * MB) return;  // need 64MB of scratch
  unsigned short* qb  = (unsigned short*)(ws + 0 * MB);   // dead after gemm_qkv
  unsigned short* kb  = (unsigned short*)(ws + 8 * MB);   // dead after gemm_qkv
  unsigned short* vb  = (unsigned short*)(ws + 16 * MB);  // dead after gemm_qkv
  unsigned short* Wqb = (unsigned short*)(ws + 24 * MB);
  unsigned short* Wkb = (unsigned short*)(ws + 26 * MB);
  unsigned short* Wvb = (unsigned short*)(ws + 28 * MB);
  unsigned short* Wob = (unsigned short*)(ws + 30 * MB);
  unsigned short* Qp  = (unsigned short*)(ws + 32 * MB);
  unsigned short* Ksw = (unsigned short*)(ws + 40 * MB);  // frag-swizzled K
  unsigned short* Vsw = (unsigned short*)(ws + 48 * MB);  // frag-swizzled V
  unsigned short* ctx = (unsigned short*)(ws + 56 * MB);
  float* outp = (float*)(ws + 8 * MB);  // 16MB over kb+vb (dead after gemm_qkv;
                                        // written by gemm_out after attn)

  // 1) fp32 -> bf16, single fused launch
  cvt_all<<<16384, 256, 0, stream>>>(q, k, v, Wq, Wk, Wv, Wo,
                                     qb, kb, vb, Wqb, Wkb, Wvb, Wob);

  // 2) Q/K/V projections; K and V written directly in attention fragment order
  gemm_qkv<<<dim3(8, 32, 3), 256, 0, stream>>>(qb, kb, vb, Wqb, Wkb, Wvb,
                                               Qp, Ksw, Vsw);

  // 3) flash attention (1 wave / 16 q-rows per block, longest-first)
  attn_kernel<<<dim3(32, 128), 64, 0, stream>>>(Qp, Ksw, Vsw, sen_len, ctx);

  // 4) output projection (fp32 out)
  gemm_out<<<dim3(8, 32), 256, 0, stream>>>(ctx, Wob, outp);

  // 5) residual + LayerNorm
  ln_kernel<<<4096, 256, 0, stream>>>(outp, q, gamma, beta, out);
}

// Round 4
// 245.543 us; speedup vs baseline: 1.3600x; 1.0736x over previous
//
#include <hip/hip_runtime.h>

// Problem constants (fixed by the reference): B=2, S=2048, D=1024, H=16, d=64.
#define SEQ 2048
#define DM  1024
#define NH  16
#define DH  64

typedef __attribute__((ext_vector_type(8))) __bf16 bf16x8;
typedef __attribute__((ext_vector_type(4))) float f32x4;

// fp32 -> bf16 (round-to-nearest-even)
__device__ inline unsigned short f2b(float f) {
  union { float f; unsigned u; } a; a.f = f;
  unsigned u = a.u;
  u += 0x7fffu + ((u >> 16) & 1u);
  return (unsigned short)(u >> 16);
}

// async global->LDS, 16B per lane; LDS dest = uniform base + lane*16
__device__ inline void glds16(const void* g, void* s) {
  __builtin_amdgcn_global_load_lds((const __attribute__((address_space(1))) void*)g,
                                   (__attribute__((address_space(3))) void*)s,
                                   16, 0, 0);
}

// One fused fp32->bf16 convert over all 7 tensors.
__global__ __launch_bounds__(256) void cvt_all(
    const float* __restrict__ q, const float* __restrict__ k,
    const float* __restrict__ v, const float* __restrict__ Wq,
    const float* __restrict__ Wk, const float* __restrict__ Wv,
    const float* __restrict__ Wo, unsigned short* __restrict__ qb,
    unsigned short* __restrict__ kb, unsigned short* __restrict__ vb,
    unsigned short* __restrict__ Wqb, unsigned short* __restrict__ Wkb,
    unsigned short* __restrict__ Wvb, unsigned short* __restrict__ Wob) {
  int blk = blockIdx.x;
  const float* src;
  unsigned short* dst;
  int rel;
  if (blk < 4096)        { src = q;  dst = qb;  rel = blk; }
  else if (blk < 8192)   { src = k;  dst = kb;  rel = blk - 4096; }
  else if (blk < 12288)  { src = v;  dst = vb;  rel = blk - 8192; }
  else if (blk < 13312)  { src = Wq; dst = Wqb; rel = blk - 12288; }
  else if (blk < 14336)  { src = Wk; dst = Wkb; rel = blk - 13312; }
  else if (blk < 15360)  { src = Wv; dst = Wvb; rel = blk - 14336; }
  else                   { src = Wo; dst = Wob; rel = blk - 15360; }
  int i = rel * 256 + threadIdx.x;
  float4 val = ((const float4*)src)[i];
  ushort4 o;
  o.x = f2b(val.x); o.y = f2b(val.y); o.z = f2b(val.z); o.w = f2b(val.w);
  ((ushort4*)dst)[i] = o;
}

// C[M,N] = A[M,K] @ Bt[N,K]^T, bf16 inputs, 128x128 tile, 4 waves (2x2 of 64x64),
// 16x16x32 bf16 MFMA. LDS staging buffers are passed in (shared across all
// template instantiations in one kernel -> single 32KB allocation, NOT 3x).
// Output MODE:
//   0 = bf16 row-major, 1 = f32 row-major,
//   2 = bf16 K-fragment-swizzle (attn QK A-frag contiguous),
//   3 = bf16 V-fragment-swizzle (attn PV B-frag contiguous).
template<int MODE>
__device__ inline void gemm_body(const unsigned short* __restrict__ A,
                                 const unsigned short* __restrict__ Bt,
                                 void* __restrict__ Cv, int N, int K,
                                 unsigned short* As, unsigned short* Bs) {
  const int tid = threadIdx.x;
  const int wave = tid >> 6, lane = tid & 63;
  const int quad = lane >> 4, l16 = lane & 15;
  const int m0 = blockIdx.y * 128, n0 = blockIdx.x * 128;
  const int wm = (wave >> 1) * 64, wn = (wave & 1) * 64;
  const int srow = lane >> 3, scol = (lane & 7) * 8;

  f32x4 acc[4][4];
#pragma unroll
  for (int i = 0; i < 4; i++)
#pragma unroll
    for (int j = 0; j < 4; j++) acc[i][j] = (f32x4)0.f;

  for (int k0 = 0; k0 < K; k0 += 64) {
#pragma unroll
    for (int c = 0; c < 4; c++) {
      int inst = wave * 4 + c;       // 16 insts cover 128 rows x 64 k
      int row = inst * 8 + srow;
      glds16(A + (size_t)(m0 + row) * K + k0 + scol, &As[inst * 512]);
      glds16(Bt + (size_t)(n0 + row) * K + k0 + scol, &Bs[inst * 512]);
    }
    __syncthreads();
#pragma unroll
    for (int ks = 0; ks < 2; ks++) {
      bf16x8 af[4], bfr[4];
#pragma unroll
      for (int i = 0; i < 4; i++)
        af[i] = *(const bf16x8*)&As[(wm + i * 16 + l16) * 64 + ks * 32 + quad * 8];
#pragma unroll
      for (int j = 0; j < 4; j++)
        bfr[j] = *(const bf16x8*)&Bs[(wn + j * 16 + l16) * 64 + ks * 32 + quad * 8];
#pragma unroll
      for (int i = 0; i < 4; i++)
#pragma unroll
        for (int j = 0; j < 4; j++)
          acc[i][j] = __builtin_amdgcn_mfma_f32_16x16x32_bf16(af[i], bfr[j],
                                                              acc[i][j], 0, 0, 0);
    }
    __syncthreads();
  }
  // C/D layout: col = lane&15, row = quad*4 + reg (m89/m91 verified)
#pragma unroll
  for (int i = 0; i < 4; i++)
#pragma unroll
    for (int j = 0; j < 4; j++)
#pragma unroll
      for (int r = 0; r < 4; r++) {
        int row = m0 + wm + i * 16 + quad * 4 + r;
        int col = n0 + wn + j * 16 + l16;
        if (MODE == 0) {
          ((unsigned short*)Cv)[(size_t)row * N + col] = f2b(acc[i][j][r]);
        } else if (MODE == 1) {
          ((float*)Cv)[(size_t)row * N + col] = acc[i][j][r];
        } else if (MODE == 2) {
          int b = row >> 11, s = row & 2047;
          int h = col >> 6, d = col & 63;
          size_t off = (((size_t)(b * NH + h) * 32 + (s >> 6)) * 8 +
                        ((s >> 4) & 3) * 2 + (d >> 5)) * 512 +
                       (((d >> 3) & 3) * 16 + (s & 15)) * 8 + (d & 7);
          ((unsigned short*)Cv)[off] = f2b(acc[i][j][r]);
        } else {
          int b = row >> 11, s = row & 2047, jj = s & 63;
          int h = col >> 6, d = col & 63;
          size_t off = (((size_t)(b * NH + h) * 32 + (s >> 6)) * 8 +
                        (jj >> 5) * 4 + (d >> 4)) * 512 +
                       (((jj >> 3) & 3) * 16 + (d & 15)) * 8 + (jj & 7);
          ((unsigned short*)Cv)[off] = f2b(acc[i][j][r]);
        }
      }
}

__global__ __launch_bounds__(256) void gemm_qkv(
    const unsigned short* __restrict__ A0, const unsigned short* __restrict__ A1,
    const unsigned short* __restrict__ A2, const unsigned short* __restrict__ B0,
    const unsigned short* __restrict__ B1, const unsigned short* __restrict__ B2,
    unsigned short* __restrict__ C0, unsigned short* __restrict__ C1,
    unsigned short* __restrict__ C2) {
  // Single shared staging allocation for all three MODE instantiations.
  // (Static __shared__ inside gemm_body allocated 3x32KB = 96KB -> 1 block/CU.)
  __shared__ unsigned short As[128 * 64];
  __shared__ unsigned short Bs[128 * 64];
  if (blockIdx.z == 0)      gemm_body<0>(A0, B0, (void*)C0, DM, DM, As, Bs);  // Q
  else if (blockIdx.z == 1) gemm_body<2>(A1, B1, (void*)C1, DM, DM, As, Bs);  // K swz
  else                      gemm_body<3>(A2, B2, (void*)C2, DM, DM, As, Bs);  // V swz
}

__global__ __launch_bounds__(256) void gemm_out(const unsigned short* __restrict__ A,
                                                const unsigned short* __restrict__ Bt,
                                                float* __restrict__ C) {
  __shared__ unsigned short As[128 * 64];
  __shared__ unsigned short Bs[128 * 64];
  gemm_body<1>(A, Bt, (void*)C, DM, DM, As, Bs);
}

// Flash attention, 1 wave per block (64 thr), 16 q-rows per wave.
// Grid: (B*H, 128 q-tiles, reversed so causal-longest first). No barriers:
// K/V fragments are contiguous coalesced 1KB loads from the swizzled layouts;
// K is register-double-buffered (prefetch chunk c+1 during chunk c), V issued
// at loop top so its latency hides behind QK-MFMA + softmax. Only LDS use is
// the per-wave P layout transform (in-order DS ops, no sync needed).
__global__ __launch_bounds__(64) void attn_kernel(const unsigned short* __restrict__ Qp,
                                                  const unsigned short* __restrict__ Ksw,
                                                  const unsigned short* __restrict__ Vsw,
                                                  const int* __restrict__ sen_len,
                                                  unsigned short* __restrict__ ctx) {
  __shared__ unsigned int Pl[16 * 36];  // P: [q][j], row stride 36 u32 (72 bf16)

  const int lane = threadIdx.x;
  const int quad = lane >> 4, l16 = lane & 15;
  const int bh = blockIdx.x, b = bh >> 4, h = bh & 15;
  const int qt = 127 - (int)blockIdx.y;  // longest (causal-late) tiles first
  const int slen = sen_len[b];
  const int qrow = qt * 16 + l16;  // this lane's q-row for softmax stats

  // Q as B-operand: lane holds Q[q=l16][d=quad*8..] (+32 for second K=32 step)
  const size_t qbase = ((size_t)b * SEQ + qrow) * DM + h * DH;
  bf16x8 qf0 = *(const bf16x8*)(Qp + qbase + quad * 8);
  bf16x8 qf1 = *(const bf16x8*)(Qp + qbase + 32 + quad * 8);

  const unsigned short* kbase = Ksw + (size_t)bh * 32 * 4096 + lane * 8;
  const unsigned short* vbase = Vsw + (size_t)bh * 32 * 4096 + lane * 8;
  const unsigned short* Pw16 = (const unsigned short*)Pl;

  int jend = qt * 16 + 16;
  if (slen < jend) jend = slen;
  const int nch = (jend + 63) >> 6;  // 64-key chunks (>=1)

  float m = -1e30f, l = 0.f;
  f32x4 o[4];
#pragma unroll
  for (int i = 0; i < 4; i++) o[i] = (f32x4)0.f;

  // preload chunk 0 K-frags (8 x contiguous 1KB)
  bf16x8 ka[4][2];
#pragma unroll
  for (int fi = 0; fi < 8; fi++)
    ka[fi >> 1][fi & 1] = *(const bf16x8*)(kbase + fi * 512);

  for (int c = 0; c < nch; ++c) {
    const int j0 = c * 64;
    // V frags for current chunk — issued first, hide behind QK + softmax
    bf16x8 vf[2][4];
#pragma unroll
    for (int fi = 0; fi < 8; fi++)
      vf[fi >> 2][fi & 3] = *(const bf16x8*)(vbase + (size_t)c * 4096 + fi * 512);
    // K frags for next chunk (clamped index: harmless dead prefetch on last)
    const int cn = (c + 1 < nch) ? c + 1 : c;
    bf16x8 kn[4][2];
#pragma unroll
    for (int fi = 0; fi < 8; fi++)
      kn[fi >> 1][fi & 1] = *(const bf16x8*)(kbase + (size_t)cn * 4096 + fi * 512);

    // S^T tiles: D[m=key][n=q]; lane holds key = kt*16 + quad*4 + r, q = l16
    f32x4 sacc[4];
#pragma unroll
    for (int kt = 0; kt < 4; kt++) sacc[kt] = (f32x4)0.f;
#pragma unroll
    for (int kt = 0; kt < 4; kt++) {
      sacc[kt] = __builtin_amdgcn_mfma_f32_16x16x32_bf16(ka[kt][0], qf0, sacc[kt], 0, 0, 0);
      sacc[kt] = __builtin_amdgcn_mfma_f32_16x16x32_bf16(ka[kt][1], qf1, sacc[kt], 0, 0, 0);
    }
    // scale + mask + per-lane max (in place in sacc)
    float cmax = -1e30f;
#pragma unroll
    for (int kt = 0; kt < 4; kt++)
#pragma unroll
      for (int r = 0; r < 4; r++) {
        int j = j0 + kt * 16 + quad * 4 + r;
        float v = (j <= qrow && j < slen) ? sacc[kt][r] * 0.125f : -1e30f;
        sacc[kt][r] = v;
        cmax = fmaxf(cmax, v);
      }
    // q-row reduction across the 4 quads holding the same q = l16
    cmax = fmaxf(cmax, __shfl_xor(cmax, 16));
    cmax = fmaxf(cmax, __shfl_xor(cmax, 32));
    float mnew = fmaxf(m, cmax);
    float alpha = __expf(m - mnew);
    float psum = 0.f;
#pragma unroll
    for (int kt = 0; kt < 4; kt++)
#pragma unroll
      for (int rp = 0; rp < 2; rp++) {
        float p0 = __expf(sacc[kt][2 * rp] - mnew);
        float p1 = __expf(sacc[kt][2 * rp + 1] - mnew);
        psum += p0 + p1;
        Pl[l16 * 36 + kt * 8 + quad * 2 + rp] =
            (unsigned)f2b(p0) | ((unsigned)f2b(p1) << 16);
      }
    psum += __shfl_xor(psum, 16);
    psum += __shfl_xor(psum, 32);
    l = l * alpha + psum;
    m = mnew;
    // rescale ctx accumulators; ctx C-layout row q = quad*4 + r -> broadcast
    // alpha from lane quad*4 + r (same wave, q-stat holder)
#pragma unroll
    for (int r = 0; r < 4; r++) {
      float ar = __shfl(alpha, quad * 4 + r);
#pragma unroll
      for (int ni = 0; ni < 4; ni++) o[ni][r] *= ar;
    }
    // PV: D[m=q][n=d] += P[q][j] V[j][d], two K=32 steps over the 64-key chunk
#pragma unroll
    for (int ko = 0; ko < 2; ko++) {
      bf16x8 pf = *(const bf16x8*)&Pw16[l16 * 72 + ko * 32 + quad * 8];
#pragma unroll
      for (int ni = 0; ni < 4; ni++)
        o[ni] = __builtin_amdgcn_mfma_f32_16x16x32_bf16(pf, vf[ko][ni], o[ni], 0, 0, 0);
    }
    // rotate K double-buffer
#pragma unroll
    for (int fi = 0; fi < 8; fi++) ka[fi >> 1][fi & 1] = kn[fi >> 1][fi & 1];
  }

  // epilogue: normalize by l (per ctx-row q = quad*4 + r) and store bf16 ctx
#pragma unroll
  for (int r = 0; r < 4; r++) {
    float lr = __shfl(l, quad * 4 + r);
    float inv = 1.0f / lr;
    int row = qt * 16 + quad * 4 + r;
#pragma unroll
    for (int ni = 0; ni < 4; ni++) {
      float v = o[ni][r] * inv;
      ctx[((size_t)b * SEQ + row) * DM + h * DH + ni * 16 + l16] = f2b(v);
    }
  }
}

// residual add + LayerNorm, one row (1024 floats) per block
__global__ __launch_bounds__(256) void ln_kernel(const float* __restrict__ xp,
                                                 const float* __restrict__ resid,
                                                 const float* __restrict__ gamma,
                                                 const float* __restrict__ beta,
                                                 float* __restrict__ out) {
  const int row = blockIdx.x;
  const int tid = threadIdx.x;
  const size_t base = (size_t)row * DM + tid * 4;
  float4 x = *(const float4*)(xp + base);
  float4 rv = *(const float4*)(resid + base);
  x.x += rv.x; x.y += rv.y; x.z += rv.z; x.w += rv.w;
  float s = x.x + x.y + x.z + x.w;
  float s2 = x.x * x.x + x.y * x.y + x.z * x.z + x.w * x.w;
#pragma unroll
  for (int off = 1; off < 64; off <<= 1) {
    s += __shfl_xor(s, off);
    s2 += __shfl_xor(s2, off);
  }
  __shared__ float sm[4], sm2[4];
  const int wave = tid >> 6, lane = tid & 63;
  if (lane == 0) { sm[wave] = s; sm2[wave] = s2; }
  __syncthreads();
  s = sm[0] + sm[1] + sm[2] + sm[3];
  s2 = sm2[0] + sm2[1] + sm2[2] + sm2[3];
  float mean = s * (1.f / 1024.f);
  float var = s2 * (1.f / 1024.f) - mean * mean;
  float rstd = rsqrtf(var + 1e-6f);
  float4 g = *(const float4*)(gamma + tid * 4);
  float4 bt = *(const float4*)(beta + tid * 4);
  float4 o;
  o.x = (x.x - mean) * rstd * g.x + bt.x;
  o.y = (x.y - mean) * rstd * g.y + bt.y;
  o.z = (x.z - mean) * rstd * g.z + bt.z;
  o.w = (x.w - mean) * rstd * g.w + bt.w;
  *(float4*)(out + base) = o;
}

extern "C" void kernel_launch(void* const* d_in, const int* in_sizes, int n_in,
                              void* d_out, int out_size, void* d_ws, size_t ws_size,
                              hipStream_t stream) {
  const float* q     = (const float*)d_in[0];
  const float* k     = (const float*)d_in[1];
  const float* v     = (const float*)d_in[2];
  const float* Wq    = (const float*)d_in[3];
  const float* Wk    = (const float*)d_in[4];
  const float* Wv    = (const float*)d_in[5];
  const float* Wo    = (const float*)d_in[6];
  const float* gamma = (const float*)d_in[7];
  const float* beta  = (const float*)d_in[8];
  const int* sen_len = (const int*)d_in[9];
  float* out = (float*)d_out;

  char* ws = (char*)d_ws;
  const size_t MB = (size_t)1 << 20;
  if (ws_size < 64 * MB) return;  // need 64MB of scratch
  unsigned short* qb  = (unsigned short*)(ws + 0 * MB);   // dead after gemm_qkv
  unsigned short* kb  = (unsigned short*)(ws + 8 * MB);   // dead after gemm_qkv
  unsigned short* vb  = (unsigned short*)(ws + 16 * MB);  // dead after gemm_qkv
  unsigned short* Wqb = (unsigned short*)(ws + 24 * MB);
  unsigned short* Wkb = (unsigned short*)(ws + 26 * MB);
  unsigned short* Wvb = (unsigned short*)(ws + 28 * MB);
  unsigned short* Wob = (unsigned short*)(ws + 30 * MB);
  unsigned short* Qp  = (unsigned short*)(ws + 32 * MB);
  unsigned short* Ksw = (unsigned short*)(ws + 40 * MB);  // frag-swizzled K
  unsigned short* Vsw = (unsigned short*)(ws + 48 * MB);  // frag-swizzled V
  unsigned short* ctx = (unsigned short*)(ws + 56 * MB);
  float* outp = (float*)(ws + 8 * MB);  // 16MB over kb+vb (dead after gemm_qkv;
                                        // written by gemm_out after attn)

  // 1) fp32 -> bf16, single fused launch
  cvt_all<<<16384, 256, 0, stream>>>(q, k, v, Wq, Wk, Wv, Wo,
                                     qb, kb, vb, Wqb, Wkb, Wvb, Wob);

  // 2) Q/K/V projections; K and V written directly in attention fragment order
  gemm_qkv<<<dim3(8, 32, 3), 256, 0, stream>>>(qb, kb, vb, Wqb, Wkb, Wvb,
                                               Qp, Ksw, Vsw);

  // 3) flash attention (1 wave / 16 q-rows per block, longest-first)
  attn_kernel<<<dim3(32, 128), 64, 0, stream>>>(Qp, Ksw, Vsw, sen_len, ctx);

  // 4) output projection (fp32 out)
  gemm_out<<<dim3(8, 32), 256, 0, stream>>>(ctx, Wob, outp);

  // 5) residual + LayerNorm
  ln_kernel<<<4096, 256, 0, stream>>>(outp, q, gamma, beta, out);
}